// Round 1
// baseline (1192.005 us; speedup 1.0000x reference)
//
#include <hip/hip_runtime.h>

typedef short s16x8 __attribute__((ext_vector_type(8)));
typedef float f32x4 __attribute__((ext_vector_type(4)));

// ---------- helpers ----------
__device__ __forceinline__ unsigned short f2bf(float f) {
    unsigned int u = __builtin_bit_cast(unsigned int, f);
    u += 0x7fffu + ((u >> 16) & 1u);           // round-to-nearest-even
    return (unsigned short)(u >> 16);
}

__device__ __forceinline__ void gload16(const void* g, void* l) {
    __builtin_amdgcn_global_load_lds(
        (const __attribute__((address_space(1))) unsigned int*)g,
        (__attribute__((address_space(3))) unsigned int*)l,
        16, 0, 0);
}

// ---------- phase 1: fp32 -> bf16 casts ----------
__global__ void cast_bf16_kernel(const float* __restrict__ src,
                                 unsigned short* __restrict__ dst, int n4) {
    int i = blockIdx.x * 256 + threadIdx.x;
    if (i >= n4) return;
    float4 v = ((const float4*)src)[i];
    ushort4 o;
    o.x = f2bf(v.x); o.y = f2bf(v.y); o.z = f2bf(v.z); o.w = f2bf(v.w);
    ((ushort4*)dst)[i] = o;
}

// ---------- phase 2: gather relative position bias rpb[h][64][64] ----------
__global__ void rpb_kernel(const float* __restrict__ table,
                           const int* __restrict__ rel,
                           float* __restrict__ rpb) {
    int t = blockIdx.x * 64 + threadIdx.x;     // 0..4095  (i*64+j)
    int idx = rel[t];
#pragma unroll
    for (int h = 0; h < 16; ++h)
        rpb[h * 4096 + t] = table[idx * 16 + h];
}

// ---------- GEMM C = A(MxK) * B(NxK)^T, bf16 in, fp32 acc ----------
// MODE 0: qkv projection epilogue (+[q_bias,0,v_bias], scatter to q/k/vt bufs, bf16)
// MODE 1: output projection epilogue (+proj_b, fp32 to out)
template <int MODE, int NCOLS>
__global__ __launch_bounds__(256) void gemm_bt(
    const unsigned short* __restrict__ A, const unsigned short* __restrict__ B,
    const float* __restrict__ bq, const float* __restrict__ bv,
    unsigned short* __restrict__ qb, unsigned short* __restrict__ kb,
    unsigned short* __restrict__ vtb,
    const float* __restrict__ pb, float* __restrict__ out) {
    __shared__ unsigned short Al[128 * 32];
    __shared__ unsigned short Bl[128 * 32];
    constexpr int NBN = NCOLS / 128;
    const int bm = blockIdx.x / NBN;
    const int bn = blockIdx.x % NBN;
    const int t = threadIdx.x;
    const int wave = t >> 6, lane = t & 63;
    const int ln = lane & 15, hk = lane >> 4;
    const int wr = (wave >> 1) * 64, wc = (wave & 1) * 64;

    const f32x4 zero = {0.f, 0.f, 0.f, 0.f};
    f32x4 acc[4][4];
#pragma unroll
    for (int i = 0; i < 4; ++i)
#pragma unroll
        for (int j = 0; j < 4; ++j) acc[i][j] = zero;

    const unsigned short* Ab = A + (size_t)bm * 128 * 512;
    const unsigned short* Bb = B + (size_t)bn * 128 * 512;
    const int row = t >> 2, cg = t & 3;   // 16B chunk (row, col-group) of the 128x32 tile

    for (int k0 = 0; k0 < 512; k0 += 32) {
        gload16(Ab + (size_t)row * 512 + k0 + cg * 8, &Al[(wave * 64) * 8]);
        gload16(Ab + (size_t)(row + 64) * 512 + k0 + cg * 8, &Al[(256 + wave * 64) * 8]);
        gload16(Bb + (size_t)row * 512 + k0 + cg * 8, &Bl[(wave * 64) * 8]);
        gload16(Bb + (size_t)(row + 64) * 512 + k0 + cg * 8, &Bl[(256 + wave * 64) * 8]);
        __syncthreads();
        s16x8 af[4], bf[4];
#pragma unroll
        for (int i = 0; i < 4; ++i)
            af[i] = *(const s16x8*)&Al[(wr + i * 16 + ln) * 32 + hk * 8];
#pragma unroll
        for (int j = 0; j < 4; ++j)
            bf[j] = *(const s16x8*)&Bl[(wc + j * 16 + ln) * 32 + hk * 8];
#pragma unroll
        for (int i = 0; i < 4; ++i)
#pragma unroll
            for (int j = 0; j < 4; ++j)
                acc[i][j] = __builtin_amdgcn_mfma_f32_16x16x32_bf16(af[i], bf[j], acc[i][j], 0, 0, 0);
        __syncthreads();
    }

    if constexpr (MODE == 0) {
#pragma unroll
        for (int i = 0; i < 4; ++i) {
            const int mbase = bm * 128 + wr + i * 16 + hk * 4;
#pragma unroll
            for (int j = 0; j < 4; ++j) {
                const int nn = bn * 128 + wc + j * 16 + ln;
                const int which = nn >> 9, rem = nn & 511;
                const int head = rem >> 5, dd = rem & 31;
                const float bias = (which == 0) ? bq[rem] : (which == 2 ? bv[rem] : 0.f);
#pragma unroll
                for (int r = 0; r < 4; ++r) {
                    const int mm = mbase + r;
                    const int b = mm >> 6, tok = mm & 63;
                    const unsigned short val = f2bf(acc[i][j][r] + bias);
                    const size_t bhb = ((size_t)(b * 16 + head)) * 2048;
                    if (which == 0)      qb[bhb + tok * 32 + dd] = val;
                    else if (which == 1) kb[bhb + tok * 32 + dd] = val;
                    else                 vtb[bhb + dd * 64 + tok] = val;  // V transposed [d][tok]
                }
            }
        }
    } else {
#pragma unroll
        for (int i = 0; i < 4; ++i) {
            const int mbase = bm * 128 + wr + i * 16 + hk * 4;
#pragma unroll
            for (int j = 0; j < 4; ++j) {
                const int nn = bn * 128 + wc + j * 16 + ln;
                const float bias = pb[nn];
#pragma unroll
                for (int r = 0; r < 4; ++r)
                    out[(size_t)(mbase + r) * NCOLS + nn] = acc[i][j][r] + bias;
            }
        }
    }
}

// ---------- phase 4: attention, one block per (b, head) ----------
__global__ __launch_bounds__(256) void attn_kernel(
    const unsigned short* __restrict__ qbuf, const unsigned short* __restrict__ kbuf,
    const unsigned short* __restrict__ vtbuf, const float* __restrict__ rpb,
    const float* __restrict__ mask, unsigned short* __restrict__ aout) {
    __shared__ unsigned short ql[64 * 32];   // Q [tok][d]
    __shared__ unsigned short kl[64 * 32];   // K [tok][d]
    __shared__ unsigned short vl[32 * 64];   // V^T [d][tok]
    __shared__ unsigned short plds[64 * 64]; // P bf16 [row][col]

    const int bh = blockIdx.x;
    const int b = bh >> 4, head = bh & 15;
    const int wmask = b & 255;               // window index = b % NW
    const int t = threadIdx.x, wave = t >> 6, lane = t & 63;
    const int ln = lane & 15, hk = lane >> 4;

    const size_t base = (size_t)bh * 2048;
    gload16(qbuf + base + t * 8, &ql[wave * 512]);
    gload16(kbuf + base + t * 8, &kl[wave * 512]);
    gload16(vtbuf + base + t * 8, &vl[wave * 512]);
    __syncthreads();

    // S = Q K^T : wave handles rows [16*wave, 16*wave+16)
    const f32x4 zero = {0.f, 0.f, 0.f, 0.f};
    s16x8 aq = *(const s16x8*)&ql[(wave * 16 + ln) * 32 + hk * 8];
    f32x4 sc[4];
#pragma unroll
    for (int j = 0; j < 4; ++j) {
        s16x8 bk = *(const s16x8*)&kl[(j * 16 + ln) * 32 + hk * 8];
        sc[j] = __builtin_amdgcn_mfma_f32_16x16x32_bf16(aq, bk, zero, 0, 0, 0);
    }

    const float scale = 0.17677669529663687f;  // 32^-0.5
    const float* rpb_h = rpb + head * 4096;
    const float* msk = mask + wmask * 4096;

    float p[4][4];
#pragma unroll
    for (int r = 0; r < 4; ++r) {
        const int i = wave * 16 + hk * 4 + r;
        float v[4], m = -1e30f;
#pragma unroll
        for (int j = 0; j < 4; ++j) {
            const int c = j * 16 + ln;
            v[j] = sc[j][r] * scale + rpb_h[i * 64 + c] + msk[i * 64 + c];
            m = fmaxf(m, v[j]);
        }
        for (int off = 1; off < 16; off <<= 1) m = fmaxf(m, __shfl_xor(m, off));
        float s = 0.f;
#pragma unroll
        for (int j = 0; j < 4; ++j) { v[j] = __expf(v[j] - m); s += v[j]; }
        for (int off = 1; off < 16; off <<= 1) s += __shfl_xor(s, off);
        const float inv = 1.f / s;
#pragma unroll
        for (int j = 0; j < 4; ++j) p[r][j] = v[j] * inv;
    }
    // C-layout -> A-operand layout round trip through LDS
#pragma unroll
    for (int r = 0; r < 4; ++r)
#pragma unroll
        for (int j = 0; j < 4; ++j)
            plds[(wave * 16 + hk * 4 + r) * 64 + j * 16 + ln] = f2bf(p[r][j]);
    __syncthreads();

    // O = P V : [16x64] x [64x32]
    f32x4 o[2] = {zero, zero};
#pragma unroll
    for (int kt = 0; kt < 2; ++kt) {
        s16x8 ap = *(const s16x8*)&plds[(wave * 16 + ln) * 64 + kt * 32 + hk * 8];
#pragma unroll
        for (int nt = 0; nt < 2; ++nt) {
            s16x8 bvf = *(const s16x8*)&vl[(nt * 16 + ln) * 64 + kt * 32 + hk * 8];
            o[nt] = __builtin_amdgcn_mfma_f32_16x16x32_bf16(ap, bvf, o[nt], 0, 0, 0);
        }
    }
    // store attn_out as [b, tok, head*32+dd] bf16 (ready for proj GEMM)
#pragma unroll
    for (int nt = 0; nt < 2; ++nt)
#pragma unroll
        for (int r = 0; r < 4; ++r) {
            const int i = wave * 16 + hk * 4 + r;
            const int dd = nt * 16 + ln;
            aout[((size_t)(b * 64 + i)) * 512 + head * 32 + dd] = f2bf(o[nt][r]);
        }
}

// ---------- launcher ----------
extern "C" void kernel_launch(void* const* d_in, const int* in_sizes, int n_in,
                              void* d_out, int out_size, void* d_ws, size_t ws_size,
                              hipStream_t stream) {
    const float* x      = (const float*)d_in[0];
    const float* mask   = (const float*)d_in[1];
    const float* qkv_w  = (const float*)d_in[2];
    const float* q_bias = (const float*)d_in[3];
    const float* v_bias = (const float*)d_in[4];
    const float* rpb_t  = (const float*)d_in[5];
    const float* proj_w = (const float*)d_in[6];
    const float* proj_b = (const float*)d_in[7];
    const int*   rel    = (const int*)d_in[8];
    float* out = (float*)d_out;

    char* ws = (char*)d_ws;
    unsigned short* xbf   = (unsigned short*)ws;                  // 128 MiB, reused as attn_out
    unsigned short* qbuf  = (unsigned short*)(ws + 0x08000000);   // 128 MiB
    unsigned short* kbuf  = (unsigned short*)(ws + 0x10000000);   // 128 MiB
    unsigned short* vtbuf = (unsigned short*)(ws + 0x18000000);   // 128 MiB
    unsigned short* wqkv  = (unsigned short*)(ws + 0x20000000);   // 1.5 MiB
    unsigned short* wproj = (unsigned short*)(ws + 0x20180000);   // 0.5 MiB
    float*          rpb   = (float*)(ws + 0x20200000);            // 0.25 MiB
    unsigned short* aout  = xbf;

    cast_bf16_kernel<<<65536, 256, 0, stream>>>(x, xbf, 16777216);
    cast_bf16_kernel<<<768, 256, 0, stream>>>(qkv_w, wqkv, 196608);
    cast_bf16_kernel<<<256, 256, 0, stream>>>(proj_w, wproj, 65536);
    rpb_kernel<<<64, 64, 0, stream>>>(rpb_t, rel, rpb);

    gemm_bt<0, 1536><<<1024 * 12, 256, 0, stream>>>(
        xbf, wqkv, q_bias, v_bias, qbuf, kbuf, vtbuf, nullptr, nullptr);

    attn_kernel<<<32768, 256, 0, stream>>>(qbuf, kbuf, vtbuf, rpb, mask, aout);

    gemm_bt<1, 512><<<1024 * 4, 256, 0, stream>>>(
        aout, wproj, nullptr, nullptr, nullptr, nullptr, nullptr, proj_b, out);
}

// Round 2
// 1078.940 us; speedup vs baseline: 1.1048x; 1.1048x over previous
//
#include <hip/hip_runtime.h>

typedef short s16x8 __attribute__((ext_vector_type(8)));
typedef float f32x4 __attribute__((ext_vector_type(4)));

// ---------- helpers ----------
__device__ __forceinline__ unsigned short f2bf(float f) {
    unsigned int u = __builtin_bit_cast(unsigned int, f);
    u += 0x7fffu + ((u >> 16) & 1u);           // round-to-nearest-even
    return (unsigned short)(u >> 16);
}

__device__ __forceinline__ void gload16(const void* g, void* l) {
    __builtin_amdgcn_global_load_lds(
        (const __attribute__((address_space(1))) unsigned int*)g,
        (__attribute__((address_space(3))) unsigned int*)l,
        16, 0, 0);
}

// ---------- phase 1: fp32 -> bf16 casts ----------
__global__ void cast_bf16_kernel(const float* __restrict__ src,
                                 unsigned short* __restrict__ dst, int n4) {
    int i = blockIdx.x * 256 + threadIdx.x;
    if (i >= n4) return;
    float4 v = ((const float4*)src)[i];
    ushort4 o;
    o.x = f2bf(v.x); o.y = f2bf(v.y); o.z = f2bf(v.z); o.w = f2bf(v.w);
    ((ushort4*)dst)[i] = o;
}

// ---------- phase 2: gather relative position bias rpb[h][64][64] ----------
__global__ void rpb_kernel(const float* __restrict__ table,
                           const int* __restrict__ rel,
                           float* __restrict__ rpb) {
    int t = blockIdx.x * 64 + threadIdx.x;     // 0..4095  (i*64+j)
    int idx = rel[t];
#pragma unroll
    for (int h = 0; h < 16; ++h)
        rpb[h * 4096 + t] = table[idx * 16 + h];
}

// ---------- GEMM C = A(MxK) * B(NxK)^T, bf16 in, fp32 acc ----------
// MODE 0: qkv projection epilogue: +[q_bias,0,v_bias], LDS-repack (swizzled),
//         coalesced 16B stores to q/k (tok-major) and v^T (d-major) buffers.
// MODE 1: output projection epilogue (+proj_b, fp32 to out, full-line stores)
template <int MODE, int NCOLS>
__global__ __launch_bounds__(256) void gemm_bt(
    const unsigned short* __restrict__ A, const unsigned short* __restrict__ B,
    const float* __restrict__ bq, const float* __restrict__ bv,
    unsigned short* __restrict__ qb, unsigned short* __restrict__ kb,
    unsigned short* __restrict__ vtb,
    const float* __restrict__ pb, float* __restrict__ out) {
    // MODE 0 epilogue needs a 128x128 bf16 tile (32KB); staging needs 16KB.
    constexpr int SMEM_SHORTS = (MODE == 0) ? 16384 : 8192;
    __shared__ unsigned short smem[SMEM_SHORTS];
    unsigned short* Al = smem;          // 128x32 tile
    unsigned short* Bl = smem + 4096;   // 128x32 tile

    constexpr int NBN = NCOLS / 128;
    const int bm = blockIdx.x / NBN;
    const int bn = blockIdx.x % NBN;
    const int t = threadIdx.x;
    const int wave = t >> 6, lane = t & 63;
    const int ln = lane & 15, hk = lane >> 4;
    const int wr = (wave >> 1) * 64, wc = (wave & 1) * 64;

    const f32x4 zero = {0.f, 0.f, 0.f, 0.f};
    f32x4 acc[4][4];
#pragma unroll
    for (int i = 0; i < 4; ++i)
#pragma unroll
        for (int j = 0; j < 4; ++j) acc[i][j] = zero;

    const unsigned short* Ab = A + (size_t)bm * 128 * 512;
    const unsigned short* Bb = B + (size_t)bn * 128 * 512;
    const int row = t >> 2, cg = t & 3;   // 16B chunk (row, col-group) of the 128x32 tile

    for (int k0 = 0; k0 < 512; k0 += 32) {
        gload16(Ab + (size_t)row * 512 + k0 + cg * 8, &Al[(wave * 64) * 8]);
        gload16(Ab + (size_t)(row + 64) * 512 + k0 + cg * 8, &Al[(256 + wave * 64) * 8]);
        gload16(Bb + (size_t)row * 512 + k0 + cg * 8, &Bl[(wave * 64) * 8]);
        gload16(Bb + (size_t)(row + 64) * 512 + k0 + cg * 8, &Bl[(256 + wave * 64) * 8]);
        __syncthreads();
        s16x8 af[4], bf[4];
#pragma unroll
        for (int i = 0; i < 4; ++i)
            af[i] = *(const s16x8*)&Al[(wr + i * 16 + ln) * 32 + hk * 8];
#pragma unroll
        for (int j = 0; j < 4; ++j)
            bf[j] = *(const s16x8*)&Bl[(wc + j * 16 + ln) * 32 + hk * 8];
#pragma unroll
        for (int i = 0; i < 4; ++i)
#pragma unroll
            for (int j = 0; j < 4; ++j)
                acc[i][j] = __builtin_amdgcn_mfma_f32_16x16x32_bf16(af[i], bf[j], acc[i][j], 0, 0, 0);
        __syncthreads();
    }

    if constexpr (MODE == 0) {
        // ---- stage 1: acc (+bias) -> swizzled LDS tile [128][128] bf16 ----
        // granule swizzle: 16B granule g at row r stored at g ^ ((r>>3)&7)
        const int which = bn >> 2;   // 0=q, 1=k, 2=v  (NCOLS=1536, NBN=12)
#pragma unroll
        for (int i = 0; i < 4; ++i) {
#pragma unroll
            for (int j = 0; j < 4; ++j) {
                const int colT = wc + j * 16 + ln;
                const int nn = bn * 128 + colT;
                const int rem = nn & 511;
                float bias = 0.f;
                if (which == 0) bias = bq[rem];
                else if (which == 2) bias = bv[rem];
                const int g = colT >> 3, cl = colT & 7;
#pragma unroll
                for (int r = 0; r < 4; ++r) {
                    const int rowT = wr + i * 16 + hk * 4 + r;
                    const int key = (rowT >> 3) & 7;
                    smem[rowT * 128 + ((g ^ key) << 3) + cl] = f2bf(acc[i][j][r] + bias);
                }
            }
        }
        __syncthreads();
        // ---- stage 2: coalesced read-back + 16B/lane global stores ----
        const int bb = bm * 2;   // tile spans windows bb, bb+1
        if (which < 2) {
            unsigned short* dst0 = (which == 0) ? qb : kb;
#pragma unroll
            for (int c = 0; c < 8; ++c) {
                const int bl = c >> 2, hl = c & 3;
                const int head = (bn & 3) * 4 + hl;
                const int rowT = bl * 64 + (t >> 2);          // tok
                const int colT = hl * 32 + (t & 3) * 8;       // dd (8-aligned)
                const int g = colT >> 3, key = (rowT >> 3) & 7;
                s16x8 val = *(const s16x8*)&smem[rowT * 128 + ((g ^ key) << 3)];
                *(s16x8*)(dst0 + ((size_t)((bb + bl) * 16 + head)) * 2048 + (size_t)t * 8) = val;
            }
        } else {
#pragma unroll
            for (int c = 0; c < 8; ++c) {
                const int bl = c >> 2, hl = c & 3;
                const int head = (bn & 3) * 4 + hl;
                const int dd = t >> 3, tok0 = (t & 7) * 8;
                const int colT = hl * 32 + dd;
                const int g = colT >> 3, cl = colT & 7;
                s16x8 val;
#pragma unroll
                for (int ii = 0; ii < 8; ++ii) {
                    const int rowT = bl * 64 + tok0 + ii;
                    const int key = (rowT >> 3) & 7;
                    val[ii] = (short)smem[rowT * 128 + ((g ^ key) << 3) + cl];
                }
                // vtb layout: [bh][dd*64 + tok] — contiguous over (dd,tok)
                *(s16x8*)(vtb + ((size_t)((bb + bl) * 16 + head)) * 2048 + (size_t)t * 8) = val;
            }
        }
    } else {
#pragma unroll
        for (int i = 0; i < 4; ++i) {
            const int mbase = bm * 128 + wr + i * 16 + hk * 4;
#pragma unroll
            for (int j = 0; j < 4; ++j) {
                const int nn = bn * 128 + wc + j * 16 + ln;
                const float bias = pb[nn];
#pragma unroll
                for (int r = 0; r < 4; ++r)
                    out[(size_t)(mbase + r) * NCOLS + nn] = acc[i][j][r] + bias;
            }
        }
    }
}

// ---------- phase 4: attention, one block per (b, head) ----------
__global__ __launch_bounds__(256) void attn_kernel(
    const unsigned short* __restrict__ qbuf, const unsigned short* __restrict__ kbuf,
    const unsigned short* __restrict__ vtbuf, const float* __restrict__ rpb,
    const float* __restrict__ mask, unsigned short* __restrict__ aout) {
    __shared__ unsigned short ql[64 * 32];   // Q [tok][d]
    __shared__ unsigned short kl[64 * 32];   // K [tok][d]
    __shared__ unsigned short vl[32 * 64];   // V^T [d][tok]
    __shared__ unsigned short plds[64 * 64]; // P bf16 [row][col]

    const int bh = blockIdx.x;
    const int b = bh >> 4, head = bh & 15;
    const int wmask = b & 255;               // window index = b % NW
    const int t = threadIdx.x, wave = t >> 6, lane = t & 63;
    const int ln = lane & 15, hk = lane >> 4;

    const size_t base = (size_t)bh * 2048;
    gload16(qbuf + base + t * 8, &ql[wave * 512]);
    gload16(kbuf + base + t * 8, &kl[wave * 512]);
    gload16(vtbuf + base + t * 8, &vl[wave * 512]);
    __syncthreads();

    // S = Q K^T : wave handles rows [16*wave, 16*wave+16)
    const f32x4 zero = {0.f, 0.f, 0.f, 0.f};
    s16x8 aq = *(const s16x8*)&ql[(wave * 16 + ln) * 32 + hk * 8];
    f32x4 sc[4];
#pragma unroll
    for (int j = 0; j < 4; ++j) {
        s16x8 bk = *(const s16x8*)&kl[(j * 16 + ln) * 32 + hk * 8];
        sc[j] = __builtin_amdgcn_mfma_f32_16x16x32_bf16(aq, bk, zero, 0, 0, 0);
    }

    const float scale = 0.17677669529663687f;  // 32^-0.5
    const float* rpb_h = rpb + head * 4096;
    const float* msk = mask + wmask * 4096;

    float p[4][4];
#pragma unroll
    for (int r = 0; r < 4; ++r) {
        const int i = wave * 16 + hk * 4 + r;
        float v[4], m = -1e30f;
#pragma unroll
        for (int j = 0; j < 4; ++j) {
            const int c = j * 16 + ln;
            v[j] = sc[j][r] * scale + rpb_h[i * 64 + c] + msk[i * 64 + c];
            m = fmaxf(m, v[j]);
        }
        for (int off = 1; off < 16; off <<= 1) m = fmaxf(m, __shfl_xor(m, off));
        float s = 0.f;
#pragma unroll
        for (int j = 0; j < 4; ++j) { v[j] = __expf(v[j] - m); s += v[j]; }
        for (int off = 1; off < 16; off <<= 1) s += __shfl_xor(s, off);
        const float inv = 1.f / s;
#pragma unroll
        for (int j = 0; j < 4; ++j) p[r][j] = v[j] * inv;
    }
    // C-layout -> A-operand layout round trip through LDS
#pragma unroll
    for (int r = 0; r < 4; ++r)
#pragma unroll
        for (int j = 0; j < 4; ++j)
            plds[(wave * 16 + hk * 4 + r) * 64 + j * 16 + ln] = f2bf(p[r][j]);
    __syncthreads();

    // O = P V : [16x64] x [64x32]
    f32x4 o[2] = {zero, zero};
#pragma unroll
    for (int kt = 0; kt < 2; ++kt) {
        s16x8 ap = *(const s16x8*)&plds[(wave * 16 + ln) * 64 + kt * 32 + hk * 8];
#pragma unroll
        for (int nt = 0; nt < 2; ++nt) {
            s16x8 bvf = *(const s16x8*)&vl[(nt * 16 + ln) * 64 + kt * 32 + hk * 8];
            o[nt] = __builtin_amdgcn_mfma_f32_16x16x32_bf16(ap, bvf, o[nt], 0, 0, 0);
        }
    }
    // store attn_out as [b, tok, head*32+dd] bf16 (ready for proj GEMM)
#pragma unroll
    for (int nt = 0; nt < 2; ++nt)
#pragma unroll
        for (int r = 0; r < 4; ++r) {
            const int i = wave * 16 + hk * 4 + r;
            const int dd = nt * 16 + ln;
            aout[((size_t)(b * 64 + i)) * 512 + head * 32 + dd] = f2bf(o[nt][r]);
        }
}

// ---------- launcher ----------
extern "C" void kernel_launch(void* const* d_in, const int* in_sizes, int n_in,
                              void* d_out, int out_size, void* d_ws, size_t ws_size,
                              hipStream_t stream) {
    const float* x      = (const float*)d_in[0];
    const float* mask   = (const float*)d_in[1];
    const float* qkv_w  = (const float*)d_in[2];
    const float* q_bias = (const float*)d_in[3];
    const float* v_bias = (const float*)d_in[4];
    const float* rpb_t  = (const float*)d_in[5];
    const float* proj_w = (const float*)d_in[6];
    const float* proj_b = (const float*)d_in[7];
    const int*   rel    = (const int*)d_in[8];
    float* out = (float*)d_out;

    char* ws = (char*)d_ws;
    unsigned short* xbf   = (unsigned short*)ws;                  // 128 MiB, reused as attn_out
    unsigned short* qbuf  = (unsigned short*)(ws + 0x08000000);   // 128 MiB
    unsigned short* kbuf  = (unsigned short*)(ws + 0x10000000);   // 128 MiB
    unsigned short* vtbuf = (unsigned short*)(ws + 0x18000000);   // 128 MiB
    unsigned short* wqkv  = (unsigned short*)(ws + 0x20000000);   // 1.5 MiB
    unsigned short* wproj = (unsigned short*)(ws + 0x20180000);   // 0.5 MiB
    float*          rpb   = (float*)(ws + 0x20200000);            // 0.25 MiB
    unsigned short* aout  = xbf;

    cast_bf16_kernel<<<65536, 256, 0, stream>>>(x, xbf, 16777216);
    cast_bf16_kernel<<<768, 256, 0, stream>>>(qkv_w, wqkv, 196608);
    cast_bf16_kernel<<<256, 256, 0, stream>>>(proj_w, wproj, 65536);
    rpb_kernel<<<64, 64, 0, stream>>>(rpb_t, rel, rpb);

    gemm_bt<0, 1536><<<1024 * 12, 256, 0, stream>>>(
        xbf, wqkv, q_bias, v_bias, qbuf, kbuf, vtbuf, nullptr, nullptr);

    attn_kernel<<<32768, 256, 0, stream>>>(qbuf, kbuf, vtbuf, rpb, mask, aout);

    gemm_bt<1, 512><<<1024 * 4, 256, 0, stream>>>(
        aout, wproj, nullptr, nullptr, nullptr, nullptr, nullptr, proj_b, out);
}